// Round 10
// baseline (1721.397 us; speedup 1.0000x reference)
//
#include <hip/hip_runtime.h>
#include <cstdint>
#include <cstddef>

// ConvGRU autoencoder, round 10: delivery-balanced design.
// Model: each step is bound by operand-delivery bytes into registers over two
// parallel pipes: LDS (~128B/cyc) and L1/L2 vector loads (~64B/cyc).
// (a) nCG=2 retile (r8's 2-cot x 2-ft waves) halves activation reads for
//     e1/d0; (b) weights split across pipes BY DESIGN: R-gates + small-layer
//     gates LDS-resident, U-gates + all candidate weights streamed from global
//     (L2-hot) -- r9 proved the compiler streams them anyway (VGPR stuck at
//     128); now the split is balanced instead of accidental.
// All waves: cg = w&1, fg = w>>1 (4 f-groups x 32 f), FTW=2.
//   e0/d1: COT=1 (co = cg*16+kb*4);  e1/d0: COT=2 (co = (2cg+i)*16+kb*4).
//
// aT (28 cb x 130 rows x 8 f16) @ byte 86016 -- layout identical to r7/r9:
//  enc: cb0 x, cb1-4 h0, cb5-12 h1, cb13 x-dup, cb14-17 rh0, cb18-25 rh1
//  dec: cb0-7 y1, cb8-15 hd0, cb16-19 hd1, cb20-27 rh
// LDS weights: enc e1R@0 (36864) e0g@36864 (24576); dec d0R@0 (49152)
//  d1g@49152 (36864). Total LDS = 86016 + 58240 = 144256.

#define F_ 128
#define T_ 100
#define B_ 64
#define ROWSP 130
#define CBSTR (ROWSP * 8)    // f16 per cb
#define CBBYTE (ROWSP * 16)  // bytes per cb
#define AT_OFF 86016
#define LDS_TOTAL (AT_OFF + 28 * CBBYTE)  // 144256

typedef _Float16 f16;
typedef __attribute__((ext_vector_type(4))) float f32x4;
typedef __attribute__((ext_vector_type(8))) _Float16 f16x8;
typedef __attribute__((ext_vector_type(4))) _Float16 f16x4;

#define MFMA(a, b, c) __builtin_amdgcn_mfma_f32_16x16x32_f16(a, b, c, 0, 0, 0)

__device__ __forceinline__ float exp2_(float x) { return __builtin_amdgcn_exp2f(x); }
__device__ __forceinline__ float rcp_(float x) { return __builtin_amdgcn_rcpf(x); }

#define KSG (-1.442695041f)  // sigmoid: sig(v) = rcp(1+exp2(v*KSG))
#define KTH (-2.885390082f)  // tanh:    tanh(v) = 2*rcp(1+exp2(v*KTH)) - 1

// cb base per (layer, ks%NC3); fragment cb = base + kb (kb = lane>>4).
__host__ __device__ constexpr int cbA(int lid, int km) {
  return lid == 0 ? (km ? 4 : 0)
       : lid == 1 ? (1 + km * 4)
       : lid == 2 ? (km * 4)
                  : (8 + km * 4);
}
__host__ __device__ constexpr int cbB(int lid, int km) {
  return lid == 0 ? (km ? 17 : 13)
       : lid == 1 ? (km == 0 ? 1 : 14 + km * 4)
       : lid == 2 ? (km < 2 ? km * 4 : 12 + km * 4)
                  : (km < 2 ? 8 + km * 4 : 20);
}

// One GRU layer step. Wave owns COT cot-tiles x 2 f-tiles. R gates from LDS
// (gRl), U gates from LDS or global (gUx), cand always global (cGb) --
// all indexed as base + (i*NK+ks)*512 f16. One internal barrier (after rh).
// Caller barriers before (inputs ready) and after (h visible).
template <int LID, int COT, int NK, int NC3, int RHOFF, bool EMITY1>
__device__ __forceinline__ void gru_layer(
    const f16* __restrict__ rdB, char* __restrict__ wrB,
    const f16* __restrict__ gRl, const f16* __restrict__ gUx,
    const f16* __restrict__ cGb,
    const f32x4* __restrict__ bR, const f32x4* __restrict__ bU,
    const f32x4* __restrict__ bC,
    f32x4* __restrict__ hreg, f16* __restrict__ y1dst) {
  // ---- conv A: R,U gates over [x ; h] ----
  f32x4 accR[COT][2], accU[COT][2];
#pragma unroll
  for (int i = 0; i < COT; ++i)
#pragma unroll
    for (int j = 0; j < 2; ++j) {
      accR[i][j] = (f32x4){0.f, 0.f, 0.f, 0.f};
      accU[i][j] = (f32x4){0.f, 0.f, 0.f, 0.f};
    }
#pragma unroll
  for (int ks = 0; ks < NK; ++ks) {
    const int k = ks / NC3, km = ks % NC3;
    const f16* fb = rdB + cbA(LID, km) * CBSTR + k * 8;
    const f16x8 b0 = *(const f16x8*)(fb);
    const f16x8 b1 = *(const f16x8*)(fb + 128);
#pragma unroll
    for (int i = 0; i < COT; ++i) {
      const f16x8 wr = *(const f16x8*)(gRl + (i * NK + ks) * 512);
      const f16x8 wu = *(const f16x8*)(gUx + (i * NK + ks) * 512);
      accR[i][0] = MFMA(wr, b0, accR[i][0]);
      accR[i][1] = MFMA(wr, b1, accR[i][1]);
      accU[i][0] = MFMA(wu, b0, accU[i][0]);
      accU[i][1] = MFMA(wu, b1, accU[i][1]);
    }
  }
  // ---- post A: rh = sigm(R)*h into rh cols (u deferred to post B) ----
#pragma unroll
  for (int i = 0; i < COT; ++i)
#pragma unroll
    for (int j = 0; j < 2; ++j) {
      f16x4 rh;
#pragma unroll
      for (int q = 0; q < 4; ++q) {
        const float r = rcp_(1.0f + exp2_(fmaf(accR[i][j][q], KSG, bR[i][q])));
        rh[q] = (f16)(r * hreg[i * 2 + j][q]);
      }
      *(f16x4*)(wrB + RHOFF + i * 2 * CBBYTE + j * 256) = rh;
    }
  __syncthreads();  // rh visible to all waves
  // ---- conv B: candidate over [x ; r*h] ----
  f32x4 accC[COT][2];
#pragma unroll
  for (int i = 0; i < COT; ++i)
#pragma unroll
    for (int j = 0; j < 2; ++j) accC[i][j] = (f32x4){0.f, 0.f, 0.f, 0.f};
#pragma unroll
  for (int ks = 0; ks < NK; ++ks) {
    const int k = ks / NC3, km = ks % NC3;
    const f16* fb = rdB + cbB(LID, km) * CBSTR + k * 8;
    const f16x8 b0 = *(const f16x8*)(fb);
    const f16x8 b1 = *(const f16x8*)(fb + 128);
#pragma unroll
    for (int i = 0; i < COT; ++i) {
      const f16x8 wc = *(const f16x8*)(cGb + (i * NK + ks) * 512);
      accC[i][0] = MFMA(wc, b0, accC[i][0]);
      accC[i][1] = MFMA(wc, b1, accC[i][1]);
    }
  }
  // ---- post B: u = sigm(U); h = h + u*(tanh(C)-h); write h; y1 emit ----
#pragma unroll
  for (int i = 0; i < COT; ++i)
#pragma unroll
    for (int j = 0; j < 2; ++j) {
      f16x4 hh;
#pragma unroll
      for (int q = 0; q < 4; ++q) {
        const float u = rcp_(1.0f + exp2_(fmaf(accU[i][j][q], KSG, bU[i][q])));
        const float r = rcp_(1.0f + exp2_(fmaf(accC[i][j][q], KTH, bC[i][q])));
        const float h = hreg[i * 2 + j][q];
        const float s = fmaf(2.0f, r, -(1.0f + h));  // tanh(C) - h
        const float hn = fmaf(u, s, h);
        hreg[i * 2 + j][q] = hn;
        hh[q] = (f16)hn;
      }
      *(f16x4*)(wrB + i * 2 * CBBYTE + j * 256) = hh;
      if constexpr (EMITY1) *(f16x4*)(y1dst + i * 2048 + j * 128) = hh;
    }
}

__global__ __launch_bounds__(512, 1) void ae_kernel(
    const f16* __restrict__ xf, float* __restrict__ out,
    const f16* __restrict__ wgE0, const f16* __restrict__ wcE0,
    const float* __restrict__ bgE0, const float* __restrict__ bcE0,
    const f16* __restrict__ wgE1, const f16* __restrict__ wcE1,
    const float* __restrict__ bgE1, const float* __restrict__ bcE1,
    const f16* __restrict__ wgD0, const f16* __restrict__ wcD0,
    const float* __restrict__ bgD0, const float* __restrict__ bcD0,
    const f16* __restrict__ wgD1, const f16* __restrict__ wcD1,
    const float* __restrict__ bgD1, const float* __restrict__ bcD1,
    const float* __restrict__ fw, const float* __restrict__ fb,
    f16* __restrict__ y1g) {
  extern __shared__ char smem[];
  f16* aT = (f16*)(smem + AT_OFF);
  char* atB = smem + AT_OFF;
  const int tid = threadIdx.x, b = blockIdx.x;
  const int w = tid >> 6, l = tid & 63;
  const int m16 = l & 15, kb = l >> 4, kb4 = kb * 4;
  const int cg = w & 1, fg = w >> 1;

  // zero aT (28 cb)
  for (int i = tid; i < 28 * CBBYTE / 16; i += 512)
    ((f32x4*)atB)[i] = (f32x4){0.f, 0.f, 0.f, 0.f};
  // enc LDS weights: e1 R-gates @0 (36864 B = 2304 x16B), e0g @36864 (1536)
  for (int i = tid; i < 2304; i += 512)
    ((f16x8*)smem)[i] = ((const f16x8*)wgE1)[i];
  for (int i = tid; i < 1536; i += 512)
    ((f16x8*)(smem + 36864))[i] = ((const f16x8*)wgE0)[i];

  // enc biases (scale folded)
  const int co2 = cg * 16 + kb4;
  const int coA = (2 * cg) * 16 + kb4, coB = (2 * cg + 1) * 16 + kb4;
  f32x4 bRe0[1], bUe0[1], bCe0[1], bRe1[2], bUe1[2], bCe1[2];
#pragma unroll
  for (int q = 0; q < 4; ++q) {
    bRe0[0][q] = bgE0[co2 + q] * KSG;
    bUe0[0][q] = bgE0[32 + co2 + q] * KSG;
    bCe0[0][q] = bcE0[co2 + q] * KTH;
    bRe1[0][q] = bgE1[coA + q] * KSG;
    bRe1[1][q] = bgE1[coB + q] * KSG;
    bUe1[0][q] = bgE1[64 + coA + q] * KSG;
    bUe1[1][q] = bgE1[64 + coB + q] * KSG;
    bCe1[0][q] = bcE1[coA + q] * KTH;
    bCe1[1][q] = bcE1[coB + q] * KTH;
  }

  // per-thread bases
  const f16* rdB = aT + kb * CBSTR + (fg * 32 + m16) * 8;
  const int rowb = (fg * 32 + m16 + 1) * 16 + (kb & 1) * 8;
  char* wrE0 = atB + (1 + cg * 2 + (kb >> 1)) * CBBYTE + rowb;
  char* wrE1 = atB + (5 + 4 * cg + (kb >> 1)) * CBBYTE + rowb;
  char* wrD0 = atB + (8 + 4 * cg + (kb >> 1)) * CBBYTE + rowb;
  char* wrD1 = atB + (16 + 2 * cg + (kb >> 1)) * CBBYTE + rowb;
  f16* y1t = y1g + (size_t)b * T_ * 8192 +
             ((4 * cg + (kb >> 1)) * 128 + fg * 32 + m16) * 8 + (kb & 1) * 4;
  // weight slice pointers (all: base + (i*NK+ks)*512)
  const f16* gRe1 = (const f16*)smem + (2 * cg * 9) * 512 + l * 8;           // LDS
  const f16* gUe1 = (const f16*)wgE1 + ((4 + 2 * cg) * 9) * 512 + l * 8;     // glob
  const f16* cGe1 = (const f16*)wcE1 + (2 * cg * 9) * 512 + l * 8;           // glob
  const f16* gRe0 = (const f16*)(smem + 36864) + (cg * 6) * 512 + l * 8;     // LDS
  const f16* gUe0 = (const f16*)(smem + 36864) + ((2 + cg) * 6) * 512 + l * 8;
  const f16* cGe0 = (const f16*)wcE0 + (cg * 6) * 512 + l * 8;               // glob

  f32x4 h0r[2], h1r[4];
#pragma unroll
  for (int j = 0; j < 2; ++j) h0r[j] = (f32x4){0.f, 0.f, 0.f, 0.f};
#pragma unroll
  for (int j = 0; j < 4; ++j) h1r[j] = (f32x4){0.f, 0.f, 0.f, 0.f};
  __syncthreads();

  // ================= encoder =================
  const f16* xb = xf + (size_t)b * T_ * F_;
  for (int t = 0; t < T_; ++t) {
    if (tid < F_) {  // x into col 0 (cb0) and dup col 104 (cb13)
      const f16 v = xb[t * F_ + tid];
      aT[(tid + 1) * 8] = v;
      aT[13 * CBSTR + (tid + 1) * 8] = v;
    }
    __syncthreads();
    gru_layer<0, 1, 6, 2, 13 * CBBYTE, false>(
        rdB, wrE0, gRe0, gUe0, cGe0, bRe0, bUe0, bCe0, h0r, nullptr);
    __syncthreads();
    gru_layer<1, 2, 9, 3, 13 * CBBYTE, true>(
        rdB, wrE1, gRe1, gUe1, cGe1, bRe1, bUe1, bCe1, h1r, y1t + t * 8192);
    __syncthreads();
  }

  // ================= switch to decoder =================
  {  // hd0 init (h1 final, same tiling); hd1 init (h0 final)
#pragma unroll
    for (int i = 0; i < 2; ++i)
#pragma unroll
      for (int j = 0; j < 2; ++j) {
        f16x4 hh;
#pragma unroll
        for (int q = 0; q < 4; ++q) hh[q] = (f16)h1r[i * 2 + j][q];
        *(f16x4*)(wrD0 + i * 2 * CBBYTE + j * 256) = hh;
      }
#pragma unroll
    for (int j = 0; j < 2; ++j) {
      f16x4 hh;
#pragma unroll
      for (int q = 0; q < 4; ++q) hh[q] = (f16)h0r[j][q];
      *(f16x4*)(wrD1 + j * 256) = hh;
    }
  }
  // dec LDS weights: d0 R-gates @0 (49152 B = 3072 x16B), d1g @49152 (2304).
  // (enc weight-LDS reads all completed at the loop-end barrier)
  for (int i = tid; i < 3072; i += 512)
    ((f16x8*)smem)[i] = ((const f16x8*)wgD0)[i];
  for (int i = tid; i < 2304; i += 512)
    ((f16x8*)(smem + 49152))[i] = ((const f16x8*)wgD1)[i];
  // dec biases
  f32x4 bRd0[2], bUd0[2], bCd0[2], bRd1[1], bUd1[1], bCd1[1];
#pragma unroll
  for (int q = 0; q < 4; ++q) {
    bRd0[0][q] = bgD0[coA + q] * KSG;
    bRd0[1][q] = bgD0[coB + q] * KSG;
    bUd0[0][q] = bgD0[64 + coA + q] * KSG;
    bUd0[1][q] = bgD0[64 + coB + q] * KSG;
    bCd0[0][q] = bcD0[coA + q] * KTH;
    bCd0[1][q] = bcD0[coB + q] * KTH;
    bRd1[0][q] = bgD1[co2 + q] * KSG;
    bUd1[0][q] = bgD1[32 + co2 + q] * KSG;
    bCd1[0][q] = bcD1[co2 + q] * KTH;
  }
  const f16* gRd0 = (const f16*)smem + (2 * cg * 12) * 512 + l * 8;          // LDS
  const f16* gUd0 = (const f16*)wgD0 + ((4 + 2 * cg) * 12) * 512 + l * 8;    // glob
  const f16* cGd0 = (const f16*)wcD0 + (2 * cg * 12) * 512 + l * 8;          // glob
  const f16* gRd1 = (const f16*)(smem + 49152) + (cg * 9) * 512 + l * 8;     // LDS
  const f16* gUd1 = (const f16*)(smem + 49152) + ((2 + cg) * 9) * 512 + l * 8;
  const f16* cGd1 = (const f16*)wcD1 + (cg * 9) * 512 + l * 8;               // glob
  __syncthreads();

  // ================= decoder =================
  for (int t = 0; t < T_; ++t) {
    {  // ingest y1(t) -> cb0-7
      const f16x8* src = (const f16x8*)(y1g + ((size_t)b * T_ + t) * 8192);
#pragma unroll
      for (int k2 = 0; k2 < 2; ++k2) {
        const int i = tid + k2 * 512;
        *(f16x8*)&aT[(i >> 7) * CBSTR + ((i & 127) + 1) * 8] = src[i];
      }
    }
    __syncthreads();
    gru_layer<2, 2, 12, 4, 12 * CBBYTE, false>(
        rdB, wrD0, gRd0, gUd0, cGd0, bRd0, bUd0, bCd0, h1r, nullptr);
    __syncthreads();
    gru_layer<3, 1, 9, 3, 4 * CBBYTE, false>(
        rdB, wrD1, gRd1, gUd1, cGd1, bRd1, bUd1, bCd1, h0r, nullptr);
    __syncthreads();
    if (tid < F_) {  // final 1x1 conv over hd1 (cb16-19)
      float s = fb[0];
#pragma unroll
      for (int cb = 0; cb < 4; ++cb) {
        const f16x8 h8 = *(const f16x8*)&aT[(16 + cb) * CBSTR + (tid + 1) * 8];
#pragma unroll
        for (int q = 0; q < 8; ++q) s = fmaf(fw[cb * 8 + q], (float)h8[q], s);
      }
      out[((size_t)b * T_ + t) * F_ + tid] = s;
    }
  }
}

// (CO,CI,3,3) fp32 -> f16 packed per MFMA A-fragment:
// dst[((cot*NK+ks)*64+lane)*8+j] = W[cot*16+(lane&15)][kk=ks*32+(lane>>4)*8+j]
__global__ void repack_f16(const float* __restrict__ src, f16* __restrict__ dst,
                           int CO, int CI, int CINH, int NK, int e0map) {
  const int n = (CO / 16) * NK * 64;
  for (int i = blockIdx.x * blockDim.x + threadIdx.x; i < n;
       i += gridDim.x * blockDim.x) {
    const int cot = i / (NK * 64);
    const int r = i - cot * NK * 64;
    const int ks = r >> 6, lph = r & 63;
    const int co = cot * 16 + (lph & 15);
    const int kbl = lph >> 4;
#pragma unroll
    for (int j = 0; j < 8; ++j) {
      const int kk = ks * 32 + kbl * 8 + j;
      const int k = kk / CINH, c = kk - k * CINH;
      int ci;
      if (e0map) ci = (c == 0) ? 0 : ((c >= 8 && c < 40) ? c - 7 : -1);
      else ci = (c < CI) ? c : -1;
      float wv = 0.f;
      if (ci >= 0) wv = src[((size_t)(co * CI + ci) * 3 + k) * 3 + 1];
      dst[(size_t)i * 8 + j] = (f16)wv;
    }
  }
}

__global__ void xcvt(const float* __restrict__ x, f16* __restrict__ xf, int n4) {
  for (int i = blockIdx.x * blockDim.x + threadIdx.x; i < n4;
       i += gridDim.x * blockDim.x) {
    const float4 v = ((const float4*)x)[i];
    f16x4 o;
    o[0] = (f16)v.x; o[1] = (f16)v.y; o[2] = (f16)v.z; o[3] = (f16)v.w;
    ((f16x4*)xf)[i] = o;
  }
}

extern "C" void kernel_launch(void* const* d_in, const int* in_sizes, int n_in,
                              void* d_out, int out_size, void* d_ws, size_t ws_size,
                              hipStream_t stream) {
  (void)in_sizes; (void)n_in; (void)out_size; (void)ws_size;
  const float* x = (const float*)d_in[0];
  const float* e0_wg = (const float*)d_in[1];
  const float* e0_bg = (const float*)d_in[2];
  const float* e0_wc = (const float*)d_in[3];
  const float* e0_bc = (const float*)d_in[4];
  const float* e1_wg = (const float*)d_in[5];
  const float* e1_bg = (const float*)d_in[6];
  const float* e1_wc = (const float*)d_in[7];
  const float* e1_bc = (const float*)d_in[8];
  const float* d0_wg = (const float*)d_in[9];
  const float* d0_bg = (const float*)d_in[10];
  const float* d0_wc = (const float*)d_in[11];
  const float* d0_bc = (const float*)d_in[12];
  const float* d1_wg = (const float*)d_in[13];
  const float* d1_bg = (const float*)d_in[14];
  const float* d1_wc = (const float*)d_in[15];
  const float* d1_bc = (const float*)d_in[16];
  const float* fw = (const float*)d_in[17];
  const float* fb = (const float*)d_in[18];
  float* out = (float*)d_out;

  char* p = (char*)d_ws;
  f16* y1g = (f16*)p;
  p += (size_t)B_ * T_ * 64 * 128 * 2;  // 104.86 MB
  f16* xf = (f16*)p;
  p += (size_t)B_ * T_ * F_ * 2;        // 1.64 MB
  auto aw = [&](int n) { f16* q = (f16*)p; p += (size_t)n * 2; return q; };
  f16* wgE0 = aw(64 * 192);
  f16* wcE0 = aw(32 * 192);
  f16* wgE1 = aw(128 * 288);
  f16* wcE1 = aw(64 * 288);
  f16* wgD0 = aw(128 * 384);
  f16* wcD0 = aw(64 * 384);
  f16* wgD1 = aw(64 * 288);
  f16* wcD1 = aw(32 * 288);

  auto rp = [&](const float* s, f16* d, int CO, int CI, int CINH, int e0m) {
    const int NK = 3 * CINH / 32;
    const int n = (CO / 16) * NK * 64;
    hipLaunchKernelGGL(repack_f16, dim3((n + 255) / 256), dim3(256), 0, stream,
                       s, d, CO, CI, CINH, NK, e0m);
  };
  rp(e0_wg, wgE0, 64, 33, 64, 1);
  rp(e0_wc, wcE0, 32, 33, 64, 1);
  rp(e1_wg, wgE1, 128, 96, 96, 0);
  rp(e1_wc, wcE1, 64, 96, 96, 0);
  rp(d0_wg, wgD0, 128, 128, 128, 0);
  rp(d0_wc, wcD0, 64, 128, 128, 0);
  rp(d1_wg, wgD1, 64, 96, 96, 0);
  rp(d1_wc, wcD1, 32, 96, 96, 0);
  hipLaunchKernelGGL(xcvt, dim3(200), dim3(1024), 0, stream, x, xf,
                     B_ * T_ * F_ / 4);

  hipFuncSetAttribute((const void*)ae_kernel,
                      hipFuncAttributeMaxDynamicSharedMemorySize, LDS_TOTAL);
  hipLaunchKernelGGL(ae_kernel, dim3(B_), dim3(512), LDS_TOTAL, stream, xf, out,
                     wgE0, wcE0, e0_bg, e0_bc, wgE1, wcE1, e1_bg, e1_bc,
                     wgD0, wcD0, d0_bg, d0_bc, wgD1, wcD1, d1_bg, d1_bc,
                     fw, fb, y1g);
}

// Round 11
// 1459.059 us; speedup vs baseline: 1.1798x; 1.1798x over previous
//
#include <hip/hip_runtime.h>
#include <cstdint>
#include <cstddef>

// ConvGRU autoencoder, round 11: cross-layer software pipelining in-block.
// e0(t) || e1(t-1) and d0(t) || d1(t-1) are independent -> merged into the
// same barrier windows. 3 barriers per timestep (was 5):
//   [convA both + postA both] bar [convB both] bar [postB both + ingest] bar
// postA's rh writes are cb-disjoint from all convA reads (verified); postB's
// h writes require the barrier before them (convB reads h) and after (next
// convA reads h). Tilings/placement/math = r9 (best, 1247us) verbatim.
//
// aT: 32 cb x 130 rows x 8 f16 @ byte 86016 (total LDS 152576):
//  enc: cb0 x, cb1-4 h0, cb5-12 h1, cb13 x-dup, cb14-17 rh0, cb18-25 rh1
//  dec: cb0-7 y1, cb8-15 hd0, cb16-19 hd1, cb20-27 rh_d0, cb28-31 rh_d1
// LDS weights: enc wgE0@0 wcE0@24576; dec wcD0@0 wgD1@49152 (wcD1 streamed).

#define F_ 128
#define T_ 100
#define B_ 64
#define ROWSP 130
#define CBSTR (ROWSP * 8)    // f16 per cb
#define CBBYTE (ROWSP * 16)  // bytes per cb
#define AT_OFF 86016
#define NCB 32
#define LDS_TOTAL (AT_OFF + NCB * CBBYTE)  // 152576

typedef _Float16 f16;
typedef __attribute__((ext_vector_type(4))) float f32x4;
typedef __attribute__((ext_vector_type(8))) _Float16 f16x8;
typedef __attribute__((ext_vector_type(4))) _Float16 f16x4;

#define MFMA(a, b, c) __builtin_amdgcn_mfma_f32_16x16x32_f16(a, b, c, 0, 0, 0)

__device__ __forceinline__ float exp2_(float x) { return __builtin_amdgcn_exp2f(x); }
__device__ __forceinline__ float rcp_(float x) { return __builtin_amdgcn_rcpf(x); }

#define KSG (-1.442695041f)  // sigmoid: sig(v) = rcp(1+exp2(v*KSG))
#define KTH (-2.885390082f)  // tanh:    tanh(v) = 2*rcp(1+exp2(v*KTH)) - 1

// cb base per (layer, ks%NC3); fragment cb = base + kb (kb = lane>>4).
__host__ __device__ constexpr int cbA(int lid, int km) {
  return lid == 0 ? (km ? 4 : 0)
       : lid == 1 ? (1 + km * 4)
       : lid == 2 ? (km * 4)
                  : (8 + km * 4);
}
__host__ __device__ constexpr int cbB(int lid, int km) {
  return lid == 0 ? (km ? 17 : 13)
       : lid == 1 ? (km == 0 ? 1 : 14 + km * 4)
       : lid == 2 ? (km < 2 ? km * 4 : 12 + km * 4)
                  : (km < 2 ? 8 + km * 4 : 28);
}

// Gate convs (R,U) over [x ; h]. Weights from regs (WREG) or LDS.
template <int LID, int FTW, int NK, int NC3, bool WREG>
__device__ __forceinline__ void convA_f(
    const f16* __restrict__ rdB,
    const f16x8* __restrict__ aR, const f16x8* __restrict__ aU,
    const f16* __restrict__ gR, const f16* __restrict__ gU,
    f32x4* __restrict__ accR, f32x4* __restrict__ accU) {
#pragma unroll
  for (int j = 0; j < FTW; ++j) {
    accR[j] = (f32x4){0.f, 0.f, 0.f, 0.f};
    accU[j] = (f32x4){0.f, 0.f, 0.f, 0.f};
  }
#pragma unroll
  for (int ks = 0; ks < NK; ++ks) {
    const int k = ks / NC3, km = ks % NC3;
    const f16* fb = rdB + cbA(LID, km) * CBSTR + k * 8;
    f16x8 bf[FTW];
#pragma unroll
    for (int j = 0; j < FTW; ++j) bf[j] = *(const f16x8*)(fb + j * 128);
    f16x8 wr, wu;
    if constexpr (WREG) { wr = aR[ks]; wu = aU[ks]; }
    else {
      wr = *(const f16x8*)(gR + ks * 512);
      wu = *(const f16x8*)(gU + ks * 512);
    }
#pragma unroll
    for (int j = 0; j < FTW; ++j) accR[j] = MFMA(wr, bf[j], accR[j]);
#pragma unroll
    for (int j = 0; j < FTW; ++j) accU[j] = MFMA(wu, bf[j], accU[j]);
  }
}

// Candidate conv over [x ; r*h]. Weights from regs (CREG) or LDS.
template <int LID, int FTW, int NK, int NC3, bool CREG>
__device__ __forceinline__ void convB_f(
    const f16* __restrict__ rdB, const f16x8* __restrict__ cR,
    const f16* __restrict__ cW, f32x4* __restrict__ accC) {
#pragma unroll
  for (int j = 0; j < FTW; ++j) accC[j] = (f32x4){0.f, 0.f, 0.f, 0.f};
#pragma unroll
  for (int ks = 0; ks < NK; ++ks) {
    const int k = ks / NC3, km = ks % NC3;
    const f16* fb = rdB + cbB(LID, km) * CBSTR + k * 8;
    f16x8 bf[FTW];
#pragma unroll
    for (int j = 0; j < FTW; ++j) bf[j] = *(const f16x8*)(fb + j * 128);
    f16x8 wc;
    if constexpr (CREG) wc = cR[ks];
    else wc = *(const f16x8*)(cW + ks * 512);
#pragma unroll
    for (int j = 0; j < FTW; ++j) accC[j] = MFMA(wc, bf[j], accC[j]);
  }
}

// rh = sigm(R)*h into rh cb (RHCB relative to wrB's base cb).
template <int FTW, int RHCB>
__device__ __forceinline__ void postA_f(const f32x4* __restrict__ accR,
                                        const f32x4 bR,
                                        const f32x4* __restrict__ hreg,
                                        char* __restrict__ wrB) {
#pragma unroll
  for (int j = 0; j < FTW; ++j) {
    f16x4 rh;
#pragma unroll
    for (int q = 0; q < 4; ++q) {
      const float r = rcp_(1.0f + exp2_(fmaf(accR[j][q], KSG, bR[q])));
      rh[q] = (f16)(r * hreg[j][q]);
    }
    *(f16x4*)(wrB + RHCB * CBBYTE + j * 256) = rh;
  }
}

// u = sigm(U); h = h + u*(tanh(C)-h); write h cb (+ y1 emit).
template <int FTW, int HCB, bool EMITY1>
__device__ __forceinline__ void postB_f(const f32x4* __restrict__ accU,
                                        const f32x4* __restrict__ accC,
                                        const f32x4 bU, const f32x4 bC,
                                        f32x4* __restrict__ hreg,
                                        char* __restrict__ wrB,
                                        f16* __restrict__ y1dst) {
#pragma unroll
  for (int j = 0; j < FTW; ++j) {
    f16x4 hh;
#pragma unroll
    for (int q = 0; q < 4; ++q) {
      const float u = rcp_(1.0f + exp2_(fmaf(accU[j][q], KSG, bU[q])));
      const float r = rcp_(1.0f + exp2_(fmaf(accC[j][q], KTH, bC[q])));
      const float h = hreg[j][q];
      const float s = fmaf(2.0f, r, -(1.0f + h));  // tanh(C) - h
      const float hn = fmaf(u, s, h);
      hreg[j][q] = hn;
      hh[q] = (f16)hn;
    }
    *(f16x4*)(wrB + HCB * CBBYTE + j * 256) = hh;
    if constexpr (EMITY1) *(f16x4*)(y1dst + j * 128) = hh;
  }
}

__global__ __launch_bounds__(512, 1) void ae_kernel(
    const f16* __restrict__ xf, float* __restrict__ out,
    const f16* __restrict__ wgE0, const f16* __restrict__ wcE0,
    const float* __restrict__ bgE0, const float* __restrict__ bcE0,
    const f16* __restrict__ wgE1, const f16* __restrict__ wcE1,
    const float* __restrict__ bgE1, const float* __restrict__ bcE1,
    const f16* __restrict__ wgD0, const f16* __restrict__ wcD0,
    const float* __restrict__ bgD0, const float* __restrict__ bcD0,
    const f16* __restrict__ wgD1, const f16* __restrict__ wcD1,
    const float* __restrict__ bgD1, const float* __restrict__ bcD1,
    const float* __restrict__ fw, const float* __restrict__ fb,
    f16* __restrict__ y1g) {
  extern __shared__ char smem[];
  f16* aT = (f16*)(smem + AT_OFF);
  const int tid = threadIdx.x, b = blockIdx.x;
  const int w = tid >> 6, l = tid & 63;
  const int m16 = l & 15, kb = l >> 4;

  // zero aT (32 cb)
  for (int i = tid; i < NCB * CBBYTE / 16; i += 512)
    ((f32x4*)(smem + AT_OFF))[i] = (f32x4){0.f, 0.f, 0.f, 0.f};
  // encoder LDS weights: wgE0@0 (24576 B), wcE0@24576 (12288 B)
  for (int i = tid; i < 1536; i += 512)
    ((f16x8*)(smem + 0))[i] = ((const f16x8*)wgE0)[i];
  for (int i = tid; i < 768; i += 512)
    ((f16x8*)(smem + 24576))[i] = ((const f16x8*)wcE0)[i];

  // e1 weights "in regs" (compiler streams; measured-best placement, r9)
  const int cot2 = w & 1, cot4 = w & 3;
  f16x8 wR1[9], wU1[9], wC1[9];
#pragma unroll
  for (int ks = 0; ks < 9; ++ks) {
    wR1[ks] = ((const f16x8*)wgE1)[(cot4 * 9 + ks) * 64 + l];
    wU1[ks] = ((const f16x8*)wgE1)[((cot4 + 4) * 9 + ks) * 64 + l];
    wC1[ks] = ((const f16x8*)wcE1)[(cot4 * 9 + ks) * 64 + l];
  }
  // enc biases (scale folded)
  const int co2 = cot2 * 16 + kb * 4;
  const int co4 = cot4 * 16 + kb * 4;
  f32x4 bRe0, bUe0, bCe0, bRe1, bUe1, bCe1;
#pragma unroll
  for (int q = 0; q < 4; ++q) {
    bRe0[q] = bgE0[co2 + q] * KSG;
    bUe0[q] = bgE0[32 + co2 + q] * KSG;
    bCe0[q] = bcE0[co2 + q] * KTH;
    bRe1[q] = bgE1[co4 + q] * KSG;
    bUe1[q] = bgE1[64 + co4 + q] * KSG;
    bCe1[q] = bcE1[co4 + q] * KTH;
  }
  // per-thread LDS bases (r9)
  const int ft2 = (w >> 1) * 2, ft4 = (w >> 2) * 4;
  const f16* rdB2 = aT + kb * CBSTR + (ft2 * 16 + m16) * 8;
  const f16* rdB4 = aT + kb * CBSTR + (ft4 * 16 + m16) * 8;
  char* wrB2 = (char*)aT + (cot2 * 2 + (kb >> 1)) * CBBYTE +
               (ft2 * 16 + m16 + 1) * 16 + (kb & 1) * 8;
  char* wrB4 = (char*)aT + (cot4 * 2 + (kb >> 1)) * CBBYTE +
               (ft4 * 16 + m16 + 1) * 16 + (kb & 1) * 8;
  f16* y1t = y1g + (size_t)b * T_ * 8192 +
             ((cot4 * 2 + (kb >> 1)) * 128 + ft4 * 16 + m16) * 8 + (kb & 1) * 4;
  const f16* gE0R = (const f16*)(smem + 0) + (cot2 * 6) * 512 + l * 8;
  const f16* gE0U = (const f16*)(smem + 0) + ((2 + cot2) * 6) * 512 + l * 8;
  const f16* cE0l = (const f16*)(smem + 24576) + (cot2 * 6) * 512 + l * 8;

  f32x4 h0r[2], h1r[4];
#pragma unroll
  for (int j = 0; j < 2; ++j) h0r[j] = (f32x4){0.f, 0.f, 0.f, 0.f};
#pragma unroll
  for (int j = 0; j < 4; ++j) h1r[j] = (f32x4){0.f, 0.f, 0.f, 0.f};
  __syncthreads();

  // ================= encoder: e0(t=i) || e1(t=i-1) =================
  const f16* xb = xf + (size_t)b * T_ * F_;
  if (tid < F_) {  // ingest x(0)
    const f16 v = xb[tid];
    aT[(tid + 1) * 8] = v;
    aT[13 * CBSTR + (tid + 1) * 8] = v;
  }
  __syncthreads();
  for (int i = 0; i <= T_; ++i) {
    f32x4 aR0g[2], aU0g[2], aR1g[4], aU1g[4];
    if (i < T_) convA_f<0, 2, 6, 2, false>(rdB2, nullptr, nullptr, gE0R, gE0U,
                                           aR0g, aU0g);
    if (i > 0) convA_f<1, 4, 9, 3, true>(rdB4, wR1, wU1, nullptr, nullptr,
                                         aR1g, aU1g);
    if (i < T_) postA_f<2, 14>(aR0g, bRe0, h0r, wrB2);
    if (i > 0) postA_f<4, 18>(aR1g, bRe1, h1r, wrB4);
    __syncthreads();  // rh visible
    f32x4 aC0[2], aC1[4];
    if (i < T_) convB_f<0, 2, 6, 2, false>(rdB2, nullptr, cE0l, aC0);
    if (i > 0) convB_f<1, 4, 9, 3, true>(rdB4, wC1, nullptr, aC1);
    __syncthreads();  // conv reads done -> h may be overwritten
    if (i < T_) postB_f<2, 1, false>(aU0g, aC0, bUe0, bCe0, h0r, wrB2, nullptr);
    if (i > 0) postB_f<4, 5, true>(aU1g, aC1, bUe1, bCe1, h1r, wrB4,
                                   y1t + (size_t)(i - 1) * 8192);
    if (i + 1 < T_ && tid < F_) {  // ingest x(i+1)
      const f16 v = xb[(i + 1) * F_ + tid];
      aT[(tid + 1) * 8] = v;
      aT[13 * CBSTR + (tid + 1) * 8] = v;
    }
    __syncthreads();  // h + x visible for next convA
  }

  // ================= transition to decoder =================
  {  // hd0 init = h1 final (cb8-15); hd1 init = h0 final (cb16-19)
#pragma unroll
    for (int j = 0; j < 4; ++j) {
      f16x4 hh;
#pragma unroll
      for (int q = 0; q < 4; ++q) hh[q] = (f16)h1r[j][q];
      *(f16x4*)(wrB4 + 8 * CBBYTE + j * 256) = hh;
    }
#pragma unroll
    for (int j = 0; j < 2; ++j) {
      f16x4 hh;
#pragma unroll
      for (int q = 0; q < 4; ++q) hh[q] = (f16)h0r[j][q];
      *(f16x4*)(wrB2 + 16 * CBBYTE + j * 256) = hh;
    }
  }
  // dec LDS weights: wcD0@0 (49152 B), wgD1@49152 (36864 B)
  for (int i = tid; i < 3072; i += 512)
    ((f16x8*)(smem + 0))[i] = ((const f16x8*)wcD0)[i];
  for (int i = tid; i < 2304; i += 512)
    ((f16x8*)(smem + 49152))[i] = ((const f16x8*)wgD1)[i];
  // d0 gates + d1 cand "in regs" (streamed)
  f16x8 wRd0[12], wUd0[12], wCd1[9];
#pragma unroll
  for (int ks = 0; ks < 12; ++ks) {
    wRd0[ks] = ((const f16x8*)wgD0)[(cot4 * 12 + ks) * 64 + l];
    wUd0[ks] = ((const f16x8*)wgD0)[((cot4 + 4) * 12 + ks) * 64 + l];
  }
#pragma unroll
  for (int ks = 0; ks < 9; ++ks)
    wCd1[ks] = ((const f16x8*)wcD1)[(cot2 * 9 + ks) * 64 + l];
  // dec biases
  f32x4 bRd0, bUd0, bCd0, bRd1, bUd1, bCd1;
#pragma unroll
  for (int q = 0; q < 4; ++q) {
    bRd0[q] = bgD0[co4 + q] * KSG;
    bUd0[q] = bgD0[64 + co4 + q] * KSG;
    bCd0[q] = bcD0[co4 + q] * KTH;
    bRd1[q] = bgD1[co2 + q] * KSG;
    bUd1[q] = bgD1[32 + co2 + q] * KSG;
    bCd1[q] = bcD1[co2 + q] * KTH;
  }
  const f16* cD0l = (const f16*)(smem + 0) + (cot4 * 12) * 512 + l * 8;
  const f16* gD1R = (const f16*)(smem + 49152) + (cot2 * 9) * 512 + l * 8;
  const f16* gD1U = (const f16*)(smem + 49152) + ((2 + cot2) * 9) * 512 + l * 8;
  const float fb0 = fb[0];
  __syncthreads();
  {  // ingest y1(0)
    const f16x8* src = (const f16x8*)(y1g + (size_t)b * T_ * 8192);
#pragma unroll
    for (int k2 = 0; k2 < 2; ++k2) {
      const int i = tid + k2 * 512;
      *(f16x8*)&aT[(i >> 7) * CBSTR + ((i & 127) + 1) * 8] = src[i];
    }
  }
  __syncthreads();

  // ================= decoder: d0(t=i) || d1(t=i-1), out(t=i-2) =============
  for (int i = 0; i <= T_ + 1; ++i) {
    f32x4 aRd0[4], aUd0[4], aRd1[2], aUd1[2];
    if (i < T_) convA_f<2, 4, 12, 4, true>(rdB4, wRd0, wUd0, nullptr, nullptr,
                                           aRd0, aUd0);
    if (i >= 1 && i <= T_)
      convA_f<3, 2, 9, 3, false>(rdB2, nullptr, nullptr, gD1R, gD1U, aRd1, aUd1);
    if (i >= 2 && tid < F_) {  // out(t=i-2) from hd1 cb16-19 (stable this phase)
      float s = fb0;
#pragma unroll
      for (int cb = 0; cb < 4; ++cb) {
        const f16x8 h8 = *(const f16x8*)&aT[(16 + cb) * CBSTR + (tid + 1) * 8];
#pragma unroll
        for (int q = 0; q < 8; ++q) s = fmaf(fw[cb * 8 + q], (float)h8[q], s);
      }
      out[((size_t)b * T_ + (i - 2)) * F_ + tid] = s;
    }
    if (i < T_) postA_f<4, 20>(aRd0, bRd0, h1r, wrB4);
    if (i >= 1 && i <= T_) postA_f<2, 28>(aRd1, bRd1, h0r, wrB2);
    __syncthreads();  // rh visible
    f32x4 aCd0[4], aCd1[2];
    if (i < T_) convB_f<2, 4, 12, 4, false>(rdB4, nullptr, cD0l, aCd0);
    if (i >= 1 && i <= T_) convB_f<3, 2, 9, 3, true>(rdB2, wCd1, nullptr, aCd1);
    __syncthreads();  // conv reads done -> h may be overwritten
    if (i < T_) postB_f<4, 8, false>(aUd0, aCd0, bUd0, bCd0, h1r, wrB4, nullptr);
    if (i >= 1 && i <= T_)
      postB_f<2, 16, false>(aUd1, aCd1, bUd1, bCd1, h0r, wrB2, nullptr);
    if (i + 1 < T_) {  // ingest y1(i+1)
      const f16x8* src = (const f16x8*)(y1g + ((size_t)b * T_ + (i + 1)) * 8192);
#pragma unroll
      for (int k2 = 0; k2 < 2; ++k2) {
        const int idx = tid + k2 * 512;
        *(f16x8*)&aT[(idx >> 7) * CBSTR + ((idx & 127) + 1) * 8] = src[idx];
      }
    }
    __syncthreads();  // h + y1 visible for next convA
  }
}

// (CO,CI,3,3) fp32 -> f16 packed per MFMA A-fragment:
// dst[((cot*NK+ks)*64+lane)*8+j] = W[cot*16+(lane&15)][kk=ks*32+(lane>>4)*8+j]
__global__ void repack_f16(const float* __restrict__ src, f16* __restrict__ dst,
                           int CO, int CI, int CINH, int NK, int e0map) {
  const int n = (CO / 16) * NK * 64;
  for (int i = blockIdx.x * blockDim.x + threadIdx.x; i < n;
       i += gridDim.x * blockDim.x) {
    const int cot = i / (NK * 64);
    const int r = i - cot * NK * 64;
    const int ks = r >> 6, lph = r & 63;
    const int co = cot * 16 + (lph & 15);
    const int kbl = lph >> 4;
#pragma unroll
    for (int j = 0; j < 8; ++j) {
      const int kk = ks * 32 + kbl * 8 + j;
      const int k = kk / CINH, c = kk - k * CINH;
      int ci;
      if (e0map) ci = (c == 0) ? 0 : ((c >= 8 && c < 40) ? c - 7 : -1);
      else ci = (c < CI) ? c : -1;
      float wv = 0.f;
      if (ci >= 0) wv = src[((size_t)(co * CI + ci) * 3 + k) * 3 + 1];
      dst[(size_t)i * 8 + j] = (f16)wv;
    }
  }
}

__global__ void xcvt(const float* __restrict__ x, f16* __restrict__ xf, int n4) {
  for (int i = blockIdx.x * blockDim.x + threadIdx.x; i < n4;
       i += gridDim.x * blockDim.x) {
    const float4 v = ((const float4*)x)[i];
    f16x4 o;
    o[0] = (f16)v.x; o[1] = (f16)v.y; o[2] = (f16)v.z; o[3] = (f16)v.w;
    ((f16x4*)xf)[i] = o;
  }
}

extern "C" void kernel_launch(void* const* d_in, const int* in_sizes, int n_in,
                              void* d_out, int out_size, void* d_ws, size_t ws_size,
                              hipStream_t stream) {
  (void)in_sizes; (void)n_in; (void)out_size; (void)ws_size;
  const float* x = (const float*)d_in[0];
  const float* e0_wg = (const float*)d_in[1];
  const float* e0_bg = (const float*)d_in[2];
  const float* e0_wc = (const float*)d_in[3];
  const float* e0_bc = (const float*)d_in[4];
  const float* e1_wg = (const float*)d_in[5];
  const float* e1_bg = (const float*)d_in[6];
  const float* e1_wc = (const float*)d_in[7];
  const float* e1_bc = (const float*)d_in[8];
  const float* d0_wg = (const float*)d_in[9];
  const float* d0_bg = (const float*)d_in[10];
  const float* d0_wc = (const float*)d_in[11];
  const float* d0_bc = (const float*)d_in[12];
  const float* d1_wg = (const float*)d_in[13];
  const float* d1_bg = (const float*)d_in[14];
  const float* d1_wc = (const float*)d_in[15];
  const float* d1_bc = (const float*)d_in[16];
  const float* fw = (const float*)d_in[17];
  const float* fb = (const float*)d_in[18];
  float* out = (float*)d_out;

  char* p = (char*)d_ws;
  f16* y1g = (f16*)p;
  p += (size_t)B_ * T_ * 64 * 128 * 2;  // 104.86 MB
  f16* xf = (f16*)p;
  p += (size_t)B_ * T_ * F_ * 2;        // 1.64 MB
  auto aw = [&](int n) { f16* q = (f16*)p; p += (size_t)n * 2; return q; };
  f16* wgE0 = aw(64 * 192);
  f16* wcE0 = aw(32 * 192);
  f16* wgE1 = aw(128 * 288);
  f16* wcE1 = aw(64 * 288);
  f16* wgD0 = aw(128 * 384);
  f16* wcD0 = aw(64 * 384);
  f16* wgD1 = aw(64 * 288);
  f16* wcD1 = aw(32 * 288);

  auto rp = [&](const float* s, f16* d, int CO, int CI, int CINH, int e0m) {
    const int NK = 3 * CINH / 32;
    const int n = (CO / 16) * NK * 64;
    hipLaunchKernelGGL(repack_f16, dim3((n + 255) / 256), dim3(256), 0, stream,
                       s, d, CO, CI, CINH, NK, e0m);
  };
  rp(e0_wg, wgE0, 64, 33, 64, 1);
  rp(e0_wc, wcE0, 32, 33, 64, 1);
  rp(e1_wg, wgE1, 128, 96, 96, 0);
  rp(e1_wc, wcE1, 64, 96, 96, 0);
  rp(d0_wg, wgD0, 128, 128, 128, 0);
  rp(d0_wc, wcD0, 64, 128, 128, 0);
  rp(d1_wg, wgD1, 64, 96, 96, 0);
  rp(d1_wc, wcD1, 32, 96, 96, 0);
  hipLaunchKernelGGL(xcvt, dim3(200), dim3(1024), 0, stream, x, xf,
                     B_ * T_ * F_ / 4);

  hipFuncSetAttribute((const void*)ae_kernel,
                      hipFuncAttributeMaxDynamicSharedMemorySize, LDS_TOTAL);
  hipLaunchKernelGGL(ae_kernel, dim3(B_), dim3(512), LDS_TOTAL, stream, xf, out,
                     wgE0, wcE0, e0_bg, e0_bc, wgE1, wcE1, e1_bg, e1_bc,
                     wgD0, wcD0, d0_bg, d0_bc, wgD1, wcD1, d1_bg, d1_bc,
                     fw, fb, y1g);
}

// Round 12
// 1166.363 us; speedup vs baseline: 1.4759x; 1.2509x over previous
//
#include <hip/hip_runtime.h>
#include <cstdint>
#include <cstddef>

// ConvGRU autoencoder, round 12: r9 + async ingest (4 windows/t, was 5).
// r9's tilings / weight placement / cb maps / math are unchanged. Only the
// schedule differs:
//  enc t: W2[e0A+postA; issue x(t+1)->reg] | W3[e0B+postB] |
//         W4[e1A+postA; reg->LDS x(t+1)]  | W5[e1B+postB+y1emit]
//  dec t: W2[d0A+postA; out(t-1); issue y1(t+1)->reg] | W3[d0B+postB] |
//         W4[d1A+postA; reg->LDS y1(t+1)] | W5[d1B+postB]   (+ out(T-1) epi)
// Hazards (cb granularity): x/y1 LDS region cb0-7(+13) is read only in W2/W3
// -> W4 write OK; out reads cb16-19, written only in W5 -> W2 read OK;
// rh regions cb14-25 / cb20-27 written/consumed with a barrier between.

#define F_ 128
#define T_ 100
#define B_ 64
#define ROWSP 130
#define CBSTR (ROWSP * 8)    // f16 per cb
#define CBBYTE (ROWSP * 16)  // bytes per cb
#define AT_OFF 104448
#define LDS_TOTAL (AT_OFF + 28 * CBBYTE)  // 162688

typedef _Float16 f16;
typedef __attribute__((ext_vector_type(4))) float f32x4;
typedef __attribute__((ext_vector_type(8))) _Float16 f16x8;
typedef __attribute__((ext_vector_type(4))) _Float16 f16x4;

#define MFMA(a, b, c) __builtin_amdgcn_mfma_f32_16x16x32_f16(a, b, c, 0, 0, 0)

__device__ __forceinline__ float exp2_(float x) { return __builtin_amdgcn_exp2f(x); }
__device__ __forceinline__ float rcp_(float x) { return __builtin_amdgcn_rcpf(x); }

#define KSG (-1.442695041f)  // sigmoid: sig(v) = rcp(1+exp2(v*KSG))
#define KTH (-2.885390082f)  // tanh:    tanh(v) = 2*rcp(1+exp2(v*KTH)) - 1

// cb base per (layer, ks%NC3); fragment cb = base + kb (kb = lane>>4). (r9)
__host__ __device__ constexpr int cbA(int lid, int km) {
  return lid == 0 ? (km ? 4 : 0)
       : lid == 1 ? (1 + km * 4)
       : lid == 2 ? (km * 4)
                  : (8 + km * 4);
}
__host__ __device__ constexpr int cbB(int lid, int km) {
  return lid == 0 ? (km ? 17 : 13)
       : lid == 1 ? (km == 0 ? 1 : 14 + km * 4)
       : lid == 2 ? (km < 2 ? km * 4 : 12 + km * 4)
                  : (km < 2 ? 8 + km * 4 : 20);
}

// Gate convs (R,U) over [x ; h]. Weights from regs (WREG) or LDS.
template <int LID, int FTW, int NK, int NC3, bool WREG>
__device__ __forceinline__ void convA_f(
    const f16* __restrict__ rdB,
    const f16x8* __restrict__ aR, const f16x8* __restrict__ aU,
    const f16* __restrict__ gR, const f16* __restrict__ gU,
    f32x4* __restrict__ accR, f32x4* __restrict__ accU) {
#pragma unroll
  for (int j = 0; j < FTW; ++j) {
    accR[j] = (f32x4){0.f, 0.f, 0.f, 0.f};
    accU[j] = (f32x4){0.f, 0.f, 0.f, 0.f};
  }
#pragma unroll
  for (int ks = 0; ks < NK; ++ks) {
    const int k = ks / NC3, km = ks % NC3;
    const f16* fb = rdB + cbA(LID, km) * CBSTR + k * 8;
    f16x8 bf[FTW];
#pragma unroll
    for (int j = 0; j < FTW; ++j) bf[j] = *(const f16x8*)(fb + j * 128);
    f16x8 wr, wu;
    if constexpr (WREG) { wr = aR[ks]; wu = aU[ks]; }
    else {
      wr = *(const f16x8*)(gR + ks * 512);
      wu = *(const f16x8*)(gU + ks * 512);
    }
#pragma unroll
    for (int j = 0; j < FTW; ++j) accR[j] = MFMA(wr, bf[j], accR[j]);
#pragma unroll
    for (int j = 0; j < FTW; ++j) accU[j] = MFMA(wu, bf[j], accU[j]);
  }
}

// Candidate conv over [x ; r*h]. Weights from regs (CREG) or LDS.
template <int LID, int FTW, int NK, int NC3, bool CREG>
__device__ __forceinline__ void convB_f(
    const f16* __restrict__ rdB, const f16x8* __restrict__ cR,
    const f16* __restrict__ cW, f32x4* __restrict__ accC) {
#pragma unroll
  for (int j = 0; j < FTW; ++j) accC[j] = (f32x4){0.f, 0.f, 0.f, 0.f};
#pragma unroll
  for (int ks = 0; ks < NK; ++ks) {
    const int k = ks / NC3, km = ks % NC3;
    const f16* fb = rdB + cbB(LID, km) * CBSTR + k * 8;
    f16x8 bf[FTW];
#pragma unroll
    for (int j = 0; j < FTW; ++j) bf[j] = *(const f16x8*)(fb + j * 128);
    f16x8 wc;
    if constexpr (CREG) wc = cR[ks];
    else wc = *(const f16x8*)(cW + ks * 512);
#pragma unroll
    for (int j = 0; j < FTW; ++j) accC[j] = MFMA(wc, bf[j], accC[j]);
  }
}

// rh = sigm(R)*h into cb RHCB (+ wave's base cb via wrB).
template <int FTW, int RHCB>
__device__ __forceinline__ void postA_f(const f32x4* __restrict__ accR,
                                        const f32x4 bR,
                                        const f32x4* __restrict__ hreg,
                                        char* __restrict__ wrB) {
#pragma unroll
  for (int j = 0; j < FTW; ++j) {
    f16x4 rh;
#pragma unroll
    for (int q = 0; q < 4; ++q) {
      const float r = rcp_(1.0f + exp2_(fmaf(accR[j][q], KSG, bR[q])));
      rh[q] = (f16)(r * hreg[j][q]);
    }
    *(f16x4*)(wrB + RHCB * CBBYTE + j * 256) = rh;
  }
}

// u = sigm(U); h = h + u*(tanh(C)-h); write h cb (+ y1 emit).
template <int FTW, int HCB, bool EMITY1>
__device__ __forceinline__ void postB_f(const f32x4* __restrict__ accU,
                                        const f32x4* __restrict__ accC,
                                        const f32x4 bU, const f32x4 bC,
                                        f32x4* __restrict__ hreg,
                                        char* __restrict__ wrB,
                                        f16* __restrict__ y1dst) {
#pragma unroll
  for (int j = 0; j < FTW; ++j) {
    f16x4 hh;
#pragma unroll
    for (int q = 0; q < 4; ++q) {
      const float u = rcp_(1.0f + exp2_(fmaf(accU[j][q], KSG, bU[q])));
      const float r = rcp_(1.0f + exp2_(fmaf(accC[j][q], KTH, bC[q])));
      const float h = hreg[j][q];
      const float s = fmaf(2.0f, r, -(1.0f + h));  // tanh(C) - h
      const float hn = fmaf(u, s, h);
      hreg[j][q] = hn;
      hh[q] = (f16)hn;
    }
    *(f16x4*)(wrB + HCB * CBBYTE + j * 256) = hh;
    if constexpr (EMITY1) *(f16x4*)(y1dst + j * 128) = hh;
  }
}

__global__ __launch_bounds__(512, 1) void ae_kernel(
    const f16* __restrict__ xf, float* __restrict__ out,
    const f16* __restrict__ wgE0, const f16* __restrict__ wcE0,
    const float* __restrict__ bgE0, const float* __restrict__ bcE0,
    const f16* __restrict__ wgE1, const f16* __restrict__ wcE1,
    const float* __restrict__ bgE1, const float* __restrict__ bcE1,
    const f16* __restrict__ wgD0, const f16* __restrict__ wcD0,
    const float* __restrict__ bgD0, const float* __restrict__ bcD0,
    const f16* __restrict__ wgD1, const f16* __restrict__ wcD1,
    const float* __restrict__ bgD1, const float* __restrict__ bcD1,
    const float* __restrict__ fw, const float* __restrict__ fb,
    f16* __restrict__ y1g) {
  extern __shared__ char smem[];
  f16* aT = (f16*)(smem + AT_OFF);
  const int tid = threadIdx.x, b = blockIdx.x;
  const int w = tid >> 6, l = tid & 63;
  const int m16 = l & 15, kb = l >> 4;

  // zero aT (28 cb)
  for (int i = tid; i < 28 * CBBYTE / 16; i += 512)
    ((f32x4*)(smem + AT_OFF))[i] = (f32x4){0.f, 0.f, 0.f, 0.f};
  // encoder LDS weights: wgE0@0 (24576 B), wcE0@24576 (12288 B)
  for (int i = tid; i < 1536; i += 512)
    ((f16x8*)(smem + 0))[i] = ((const f16x8*)wgE0)[i];
  for (int i = tid; i < 768; i += 512)
    ((f16x8*)(smem + 24576))[i] = ((const f16x8*)wcE0)[i];

  // e1 gate + cand weights (compiler streams from L2; measured-best, r9)
  const int cot2 = w & 1, cot4 = w & 3;
  f16x8 aR1[9], aU1[9], cE1[9];
#pragma unroll
  for (int ks = 0; ks < 9; ++ks) {
    aR1[ks] = ((const f16x8*)wgE1)[(cot4 * 9 + ks) * 64 + l];
    aU1[ks] = ((const f16x8*)wgE1)[((cot4 + 4) * 9 + ks) * 64 + l];
    cE1[ks] = ((const f16x8*)wcE1)[(cot4 * 9 + ks) * 64 + l];
  }
  // enc biases (scale folded)
  const int co2 = cot2 * 16 + kb * 4;
  const int co4 = cot4 * 16 + kb * 4;
  f32x4 bRe0, bUe0, bCe0, bRe1, bUe1, bCe1;
#pragma unroll
  for (int q = 0; q < 4; ++q) {
    bRe0[q] = bgE0[co2 + q] * KSG;
    bUe0[q] = bgE0[32 + co2 + q] * KSG;
    bCe0[q] = bcE0[co2 + q] * KTH;
    bRe1[q] = bgE1[co4 + q] * KSG;
    bUe1[q] = bgE1[64 + co4 + q] * KSG;
    bCe1[q] = bcE1[co4 + q] * KTH;
  }
  // per-thread LDS bases (r9)
  const int ft2 = (w >> 1) * 2, ft4 = (w >> 2) * 4;
  const f16* rdB2 = aT + kb * CBSTR + (ft2 * 16 + m16) * 8;
  const f16* rdB4 = aT + kb * CBSTR + (ft4 * 16 + m16) * 8;
  char* wrB2 = (char*)aT + (cot2 * 2 + (kb >> 1)) * CBBYTE +
               (ft2 * 16 + m16 + 1) * 16 + (kb & 1) * 8;
  char* wrB4 = (char*)aT + (cot4 * 2 + (kb >> 1)) * CBBYTE +
               (ft4 * 16 + m16 + 1) * 16 + (kb & 1) * 8;
  f16* y1t = y1g + (size_t)b * T_ * 8192 +
             ((cot4 * 2 + (kb >> 1)) * 128 + ft4 * 16 + m16) * 8 + (kb & 1) * 4;
  const f16* gE0R = (const f16*)(smem + 0) + (cot2 * 6) * 512 + l * 8;
  const f16* gE0U = (const f16*)(smem + 0) + ((2 + cot2) * 6) * 512 + l * 8;
  const f16* cE0l = (const f16*)(smem + 24576) + (cot2 * 6) * 512 + l * 8;

  f32x4 h0r[2], h1r[4];
#pragma unroll
  for (int j = 0; j < 2; ++j) h0r[j] = (f32x4){0.f, 0.f, 0.f, 0.f};
#pragma unroll
  for (int j = 0; j < 4; ++j) h1r[j] = (f32x4){0.f, 0.f, 0.f, 0.f};
  __syncthreads();

  // ================= encoder (4 windows/t) =================
  const f16* xb = xf + (size_t)b * T_ * F_;
  if (tid < F_) {  // ingest x(0)
    const f16 v = xb[tid];
    aT[(tid + 1) * 8] = v;
    aT[13 * CBSTR + (tid + 1) * 8] = v;
  }
  __syncthreads();
  for (int t = 0; t < T_; ++t) {
    // W2: e0 convA + postA ; issue x(t+1) -> reg
    f32x4 aR0g[2], aU0g[2];
    convA_f<0, 2, 6, 2, false>(rdB2, nullptr, nullptr, gE0R, gE0U, aR0g, aU0g);
    f16 xpre = (f16)0.f;
    if (t + 1 < T_ && tid < F_) xpre = xb[(t + 1) * F_ + tid];
    postA_f<2, 14>(aR0g, bRe0, h0r, wrB2);
    __syncthreads();
    // W3: e0 convB + postB
    f32x4 aC0[2];
    convB_f<0, 2, 6, 2, false>(rdB2, nullptr, cE0l, aC0);
    postB_f<2, 1, false>(aU0g, aC0, bUe0, bCe0, h0r, wrB2, nullptr);
    __syncthreads();
    // W4: e1 convA + postA ; write x(t+1) (cb0/13 not read here)
    f32x4 aR1g[4], aU1g[4];
    convA_f<1, 4, 9, 3, true>(rdB4, aR1, aU1, nullptr, nullptr, aR1g, aU1g);
    if (t + 1 < T_ && tid < F_) {
      aT[(tid + 1) * 8] = xpre;
      aT[13 * CBSTR + (tid + 1) * 8] = xpre;
    }
    postA_f<4, 18>(aR1g, bRe1, h1r, wrB4);
    __syncthreads();
    // W5: e1 convB + postB (+ y1 emit)
    f32x4 aC1[4];
    convB_f<1, 4, 9, 3, true>(rdB4, cE1, nullptr, aC1);
    postB_f<4, 5, true>(aU1g, aC1, bUe1, bCe1, h1r, wrB4,
                        y1t + (size_t)t * 8192);
    __syncthreads();
  }

  // ================= transition to decoder =================
  {  // hd0 init cols 64+ (= cb8-15, from h1r); hd1 init cols 128+ (cb16-19)
#pragma unroll
    for (int j = 0; j < 4; ++j) {
      f16x4 hh;
#pragma unroll
      for (int q = 0; q < 4; ++q) hh[q] = (f16)h1r[j][q];
      *(f16x4*)(wrB4 + 8 * CBBYTE + j * 256) = hh;
    }
#pragma unroll
    for (int j = 0; j < 2; ++j) {
      f16x4 hh;
#pragma unroll
      for (int q = 0; q < 4; ++q) hh[q] = (f16)h0r[j][q];
      *(f16x4*)(wrB2 + 16 * CBBYTE + j * 256) = hh;
    }
  }
  // dec LDS weights: wcD0@0 (49152 B), wgD1@49152 (36864 B), wcD1@86016
  for (int i = tid; i < 3072; i += 512)
    ((f16x8*)(smem + 0))[i] = ((const f16x8*)wcD0)[i];
  for (int i = tid; i < 2304; i += 512)
    ((f16x8*)(smem + 49152))[i] = ((const f16x8*)wgD1)[i];
  for (int i = tid; i < 1152; i += 512)
    ((f16x8*)(smem + 86016))[i] = ((const f16x8*)wcD1)[i];
  // d0 gate weights (streamed; r9 placement)
  f16x8 aR0[12], aU0[12];
#pragma unroll
  for (int ks = 0; ks < 12; ++ks) {
    aR0[ks] = ((const f16x8*)wgD0)[(cot4 * 12 + ks) * 64 + l];
    aU0[ks] = ((const f16x8*)wgD0)[((cot4 + 4) * 12 + ks) * 64 + l];
  }
  // dec biases
  f32x4 bRd0, bUd0, bCd0, bRd1, bUd1, bCd1;
#pragma unroll
  for (int q = 0; q < 4; ++q) {
    bRd0[q] = bgD0[co4 + q] * KSG;
    bUd0[q] = bgD0[64 + co4 + q] * KSG;
    bCd0[q] = bcD0[co4 + q] * KTH;
    bRd1[q] = bgD1[co2 + q] * KSG;
    bUd1[q] = bgD1[32 + co2 + q] * KSG;
    bCd1[q] = bcD1[co2 + q] * KTH;
  }
  const f16* cD0l = (const f16*)(smem + 0) + (cot4 * 12) * 512 + l * 8;
  const f16* gD1R = (const f16*)(smem + 49152) + (cot2 * 9) * 512 + l * 8;
  const f16* gD1U = (const f16*)(smem + 49152) + ((2 + cot2) * 9) * 512 + l * 8;
  const f16* cD1l = (const f16*)(smem + 86016) + (cot2 * 9) * 512 + l * 8;
  const float fb0 = fb[0];
  __syncthreads();
  {  // ingest y1(0)
    const f16x8* src = (const f16x8*)(y1g + (size_t)b * T_ * 8192);
#pragma unroll
    for (int k2 = 0; k2 < 2; ++k2) {
      const int i = tid + k2 * 512;
      *(f16x8*)&aT[(i >> 7) * CBSTR + ((i & 127) + 1) * 8] = src[i];
    }
  }
  __syncthreads();

  // ================= decoder (4 windows/t; out shifted 1 window) ===========
  for (int t = 0; t < T_; ++t) {
    // W2: d0 convA + postA ; out(t-1) (cb16-19 stable) ; issue y1(t+1)
    f32x4 aRd0[4], aUd0[4];
    convA_f<2, 4, 12, 4, true>(rdB4, aR0, aU0, nullptr, nullptr, aRd0, aUd0);
    if (t >= 1 && tid < F_) {
      float s = fb0;
#pragma unroll
      for (int cb = 0; cb < 4; ++cb) {
        const f16x8 h8 = *(const f16x8*)&aT[(16 + cb) * CBSTR + (tid + 1) * 8];
#pragma unroll
        for (int q = 0; q < 8; ++q) s = fmaf(fw[cb * 8 + q], (float)h8[q], s);
      }
      out[((size_t)b * T_ + (t - 1)) * F_ + tid] = s;
    }
    f16x8 yp0 = {}, yp1 = {};
    if (t + 1 < T_) {
      const f16x8* src = (const f16x8*)(y1g + ((size_t)b * T_ + t + 1) * 8192);
      yp0 = src[tid];
      yp1 = src[tid + 512];
    }
    postA_f<4, 20>(aRd0, bRd0, h1r, wrB4);
    __syncthreads();
    // W3: d0 convB + postB
    f32x4 aCd0[4];
    convB_f<2, 4, 12, 4, false>(rdB4, nullptr, cD0l, aCd0);
    postB_f<4, 8, false>(aUd0, aCd0, bUd0, bCd0, h1r, wrB4, nullptr);
    __syncthreads();
    // W4: d1 convA + postA ; write y1(t+1) -> cb0-7 (not read here)
    f32x4 aRd1[2], aUd1[2];
    convA_f<3, 2, 9, 3, false>(rdB2, nullptr, nullptr, gD1R, gD1U, aRd1, aUd1);
    if (t + 1 < T_) {
      const int i0 = tid, i1 = tid + 512;
      *(f16x8*)&aT[(i0 >> 7) * CBSTR + ((i0 & 127) + 1) * 8] = yp0;
      *(f16x8*)&aT[(i1 >> 7) * CBSTR + ((i1 & 127) + 1) * 8] = yp1;
    }
    postA_f<2, 20>(aRd1, bRd1, h0r, wrB2);
    __syncthreads();
    // W5: d1 convB + postB
    f32x4 aCd1[2];
    convB_f<3, 2, 9, 3, false>(rdB2, nullptr, cD1l, aCd1);
    postB_f<2, 16, false>(aUd1, aCd1, bUd1, bCd1, h0r, wrB2, nullptr);
    __syncthreads();
  }
  if (tid < F_) {  // epilogue: out(T-1)
    float s = fb0;
#pragma unroll
    for (int cb = 0; cb < 4; ++cb) {
      const f16x8 h8 = *(const f16x8*)&aT[(16 + cb) * CBSTR + (tid + 1) * 8];
#pragma unroll
      for (int q = 0; q < 8; ++q) s = fmaf(fw[cb * 8 + q], (float)h8[q], s);
    }
    out[((size_t)b * T_ + (T_ - 1)) * F_ + tid] = s;
  }
}

// (CO,CI,3,3) fp32 -> f16 packed per MFMA A-fragment:
// dst[((cot*NK+ks)*64+lane)*8+j] = W[cot*16+(lane&15)][kk=ks*32+(lane>>4)*8+j]
__global__ void repack_f16(const float* __restrict__ src, f16* __restrict__ dst,
                           int CO, int CI, int CINH, int NK, int e0map) {
  const int n = (CO / 16) * NK * 64;
  for (int i = blockIdx.x * blockDim.x + threadIdx.x; i < n;
       i += gridDim.x * blockDim.x) {
    const int cot = i / (NK * 64);
    const int r = i - cot * NK * 64;
    const int ks = r >> 6, lph = r & 63;
    const int co = cot * 16 + (lph & 15);
    const int kbl = lph >> 4;
#pragma unroll
    for (int j = 0; j < 8; ++j) {
      const int kk = ks * 32 + kbl * 8 + j;
      const int k = kk / CINH, c = kk - k * CINH;
      int ci;
      if (e0map) ci = (c == 0) ? 0 : ((c >= 8 && c < 40) ? c - 7 : -1);
      else ci = (c < CI) ? c : -1;
      float wv = 0.f;
      if (ci >= 0) wv = src[((size_t)(co * CI + ci) * 3 + k) * 3 + 1];
      dst[(size_t)i * 8 + j] = (f16)wv;
    }
  }
}

__global__ void xcvt(const float* __restrict__ x, f16* __restrict__ xf, int n4) {
  for (int i = blockIdx.x * blockDim.x + threadIdx.x; i < n4;
       i += gridDim.x * blockDim.x) {
    const float4 v = ((const float4*)x)[i];
    f16x4 o;
    o[0] = (f16)v.x; o[1] = (f16)v.y; o[2] = (f16)v.z; o[3] = (f16)v.w;
    ((f16x4*)xf)[i] = o;
  }
}

extern "C" void kernel_launch(void* const* d_in, const int* in_sizes, int n_in,
                              void* d_out, int out_size, void* d_ws, size_t ws_size,
                              hipStream_t stream) {
  (void)in_sizes; (void)n_in; (void)out_size; (void)ws_size;
  const float* x = (const float*)d_in[0];
  const float* e0_wg = (const float*)d_in[1];
  const float* e0_bg = (const float*)d_in[2];
  const float* e0_wc = (const float*)d_in[3];
  const float* e0_bc = (const float*)d_in[4];
  const float* e1_wg = (const float*)d_in[5];
  const float* e1_bg = (const float*)d_in[6];
  const float* e1_wc = (const float*)d_in[7];
  const float* e1_bc = (const float*)d_in[8];
  const float* d0_wg = (const float*)d_in[9];
  const float* d0_bg = (const float*)d_in[10];
  const float* d0_wc = (const float*)d_in[11];
  const float* d0_bc = (const float*)d_in[12];
  const float* d1_wg = (const float*)d_in[13];
  const float* d1_bg = (const float*)d_in[14];
  const float* d1_wc = (const float*)d_in[15];
  const float* d1_bc = (const float*)d_in[16];
  const float* fw = (const float*)d_in[17];
  const float* fb = (const float*)d_in[18];
  float* out = (float*)d_out;

  char* p = (char*)d_ws;
  f16* y1g = (f16*)p;
  p += (size_t)B_ * T_ * 64 * 128 * 2;  // 104.86 MB
  f16* xf = (f16*)p;
  p += (size_t)B_ * T_ * F_ * 2;        // 1.64 MB
  auto aw = [&](int n) { f16* q = (f16*)p; p += (size_t)n * 2; return q; };
  f16* wgE0 = aw(64 * 192);
  f16* wcE0 = aw(32 * 192);
  f16* wgE1 = aw(128 * 288);
  f16* wcE1 = aw(64 * 288);
  f16* wgD0 = aw(128 * 384);
  f16* wcD0 = aw(64 * 384);
  f16* wgD1 = aw(64 * 288);
  f16* wcD1 = aw(32 * 288);

  auto rp = [&](const float* s, f16* d, int CO, int CI, int CINH, int e0m) {
    const int NK = 3 * CINH / 32;
    const int n = (CO / 16) * NK * 64;
    hipLaunchKernelGGL(repack_f16, dim3((n + 255) / 256), dim3(256), 0, stream,
                       s, d, CO, CI, CINH, NK, e0m);
  };
  rp(e0_wg, wgE0, 64, 33, 64, 1);
  rp(e0_wc, wcE0, 32, 33, 64, 1);
  rp(e1_wg, wgE1, 128, 96, 96, 0);
  rp(e1_wc, wcE1, 64, 96, 96, 0);
  rp(d0_wg, wgD0, 128, 128, 128, 0);
  rp(d0_wc, wcD0, 64, 128, 128, 0);
  rp(d1_wg, wgD1, 64, 96, 96, 0);
  rp(d1_wc, wcD1, 32, 96, 96, 0);
  hipLaunchKernelGGL(xcvt, dim3(200), dim3(1024), 0, stream, x, xf,
                     B_ * T_ * F_ / 4);

  hipFuncSetAttribute((const void*)ae_kernel,
                      hipFuncAttributeMaxDynamicSharedMemorySize, LDS_TOTAL);
  hipLaunchKernelGGL(ae_kernel, dim3(B_), dim3(512), LDS_TOTAL, stream, xf, out,
                     wgE0, wcE0, e0_bg, e0_bc, wgE1, wcE1, e1_bg, e1_bc,
                     wgD0, wcD0, d0_bg, d0_bc, wgD1, wcD1, d1_bg, d1_bc,
                     fw, fb, y1g);
}